// Round 3
// baseline (450143.115 us; speedup 1.0000x reference)
//
#include <hip/hip_runtime.h>
#include <stdint.h>

// RNN-T greedy decode v5 — 3-round fence-free pipeline + register-tiled f64 dots.
//
// v4 post-mortem: dots were LDS-return-BW bound (8B LDS per MAC per lane;
// b128 return = 128B/cyc/CU) + 4-way bank conflicts (k-chunk stride ≡ 0 mod 32)
// -> VALUBusy 4%, 1.18e10 conflicts. v5 restructures the dots GEMM-style:
//   wave = 8 rows x 8 k-chunks (lane=(r,ks)); each lane keeps C column
//   accumulators in registers; per 2k: 1 LDS b64 (f32 h, per-lane distinct
//   address, stride 658/82 -> near-floor bank rate) + 2 cvt + C w-b128 (f64,
//   L2-resident packed slabs) + 2C FMA. LDS ~15% of VALU.
// k-partials (8 per value) reduce via small padded-LDS arrays; LUT repacked
// per-unit-group ([ug][1025][40] f32, 160B/row). Sync skeleton, candidate
// scheme, argmax tie-breaks, f64 accumulation order-safety: as v4 (verified).

typedef unsigned int u32;
typedef unsigned long long u64;

constexpr int NGB = 256;          // gate+pred blocks (64 unit-groups x 4 row-groups)
constexpr int NOB = 256;          // out blocks       (64 col-groups  x 4 row-groups)
constexpr int NBLK = NGB + NOB;   // 512 = 2 per CU

// ---- static device scratch ----
__device__ float  g_encT[1000 * 32 * 640];  // enc@Wenc + b_joint, [T][B][J]
__device__ float  g_lutP[64 * 1025 * 40];   // embed@Wx + b_lstm, packed [ug][row][gl]
__device__ double g_Wg64[64 * 50 * 640];    // packed gate-block weights [ug][50][640]
                                            //   cols 0..9 = Wpred^T(u0+j), 10..49 = Wh^T [i,f,g,o]x10
__device__ double g_WoT64[1025 * 640];      // Wout^T [V+1][J] as f64
__device__ float  g_hnew[2 * 32 * 640];     // h_new, double-buffered by parity
__device__ float  g_tnh[32 * 640];          // tanh(joint pre-act)
__device__ u64    g_cval[32 * 64];          // per-(row, col-group) best (f64 bits)
__device__ int    g_cidx[32 * 64];
__device__ u32    g_cnt[64 * 32];           // counters, 128 B apart

constexpr int F1L = 0,  F1R = 16;  // 16 leaves x 16 gate blocks
constexpr int F2L = 17, F2R = 33;  // 16 leaves x 16 gate blocks
constexpr int F3L = 34, F3R = 50;  // 16 leaves x 16 out blocks

__device__ __forceinline__ float sigmf(float x) { return 1.0f / (1.0f + expf(-x)); }

// caller: thread 0, after __syncthreads() (vmcnt-drain => data stores at MALL).
__device__ __forceinline__ void bump(int leaf, int root, int step) {
  u32 old = __hip_atomic_fetch_add(&g_cnt[leaf * 32], 1u, __ATOMIC_RELAXED, __HIP_MEMORY_SCOPE_AGENT);
  if (old + 1u == (u32)(step + 1) * 16u)
    __hip_atomic_fetch_add(&g_cnt[root * 32], 1u, __ATOMIC_RELAXED, __HIP_MEMORY_SCOPE_AGENT);
}

__device__ __forceinline__ void waitc(int root, u32 target) {
  if (threadIdx.x == 0) {
    while (__hip_atomic_load(&g_cnt[root * 32], __ATOMIC_RELAXED, __HIP_MEMORY_SCOPE_AGENT) < target)
      __builtin_amdgcn_s_sleep(1);
  }
  __syncthreads();
}

// stage 8 rows x 640 f32 (MALL-coherent u64 loads) -> LDS f32, swizzled
// layout: addr = r*658 + ks*82 + j  (k = ks*80 + j); strides 658/82 ≡ 18 mod 32.
__device__ __forceinline__ void stage8f(const float* gsrc, float* dst, int tid) {
  const u64* src = (const u64*)gsrc;
#pragma unroll
  for (int i = 0; i < 10; i++) {
    int idx = tid + i * 256;  // < 2560
    u64 v = __hip_atomic_load((u64*)(src + idx), __ATOMIC_RELAXED, __HIP_MEMORY_SCOPE_AGENT);
    int p2 = idx * 2;
    int r = p2 / 640, k0 = p2 - r * 640;
    int ks = k0 / 80, j = k0 - ks * 80;
    float2 f;
    f.x = __uint_as_float((u32)v);
    f.y = __uint_as_float((u32)(v >> 32));
    *(float2*)&dst[r * 658 + ks * 82 + j] = f;
  }
}

// ---------------- precompute: LUT = embed @ Wx + b_lstm, packed per ug ----------
__global__ __launch_bounds__(256) void k_lut(const float* __restrict__ embed,
                                             const float* __restrict__ Wx,
                                             const float* __restrict__ b_lstm) {
  const int tid = threadIdx.x;
  const int cg = blockIdx.x % 10, rg = blockIdx.x / 10;  // rg 0..128
  const int c = cg * 256 + tid;
  const int r0 = rg * 8;
  double acc[8];
  double bl = (double)b_lstm[c];
#pragma unroll
  for (int i = 0; i < 8; i++) acc[i] = bl;
  for (int e = 0; e < 640; e++) {
    double wx = (double)Wx[(size_t)e * 2560 + c];
#pragma unroll
    for (int i = 0; i < 8; i++) {
      int r = r0 + i;
      if (r < 1024) acc[i] += (double)embed[(size_t)r * 640 + e] * wx;
    }
  }
  const int gi = c / 640, cw = c - gi * 640;
  const int ug = cw / 10, ul = cw - ug * 10;
  const int gl = gi * 10 + ul;
#pragma unroll
  for (int i = 0; i < 8; i++) {
    int r = r0 + i;
    if (r < 1025) g_lutP[((size_t)ug * 1025 + r) * 40 + gl] = (float)acc[i];
  }
  if (blockIdx.x == 0) {  // re-init counters every call (graph replay)
    for (int i = tid; i < 64 * 32; i += 256) g_cnt[i] = 0u;
  }
}

// ------------- precompute: encT[t][b][j] = sum_d enc[b][d][t]*Wenc[d][j] + b_joint[j] --
__global__ __launch_bounds__(256) void k_encproj(const float* __restrict__ enc,
                                                 const float* __restrict__ Wenc,
                                                 const float* __restrict__ bj) {
  __shared__ __align__(16) float As[16][68];
  __shared__ __align__(16) float Bs[16][68];
  const int tid = threadIdx.x;
  const int jt = blockIdx.x % 10, tt = blockIdx.x / 10;  // 10 j-tiles, 16 t-tiles
  const int b = blockIdx.y;
  const int t0 = tt * 64, j0 = jt * 64;
  const int ty = tid >> 4, tx = tid & 15;
  double acc[4][4] = {};
  const float* Ab = enc + (size_t)b * 640 * 1000;
  for (int d0 = 0; d0 < 640; d0 += 16) {
#pragma unroll
    for (int i = 0; i < 4; i++) {
      int idx = tid + i * 256;
      int d = idx >> 6, t = idx & 63;
      As[d][t] = (t0 + t < 1000) ? Ab[(size_t)(d0 + d) * 1000 + t0 + t] : 0.f;
      Bs[d][t] = Wenc[(size_t)(d0 + d) * 640 + j0 + t];
    }
    __syncthreads();
#pragma unroll
    for (int kk = 0; kk < 16; kk++) {
      float4 av = *(const float4*)&As[kk][ty * 4];
      float4 bv = *(const float4*)&Bs[kk][tx * 4];
      float a[4] = {av.x, av.y, av.z, av.w};
      float bb[4] = {bv.x, bv.y, bv.z, bv.w};
#pragma unroll
      for (int i = 0; i < 4; i++)
#pragma unroll
        for (int j = 0; j < 4; j++) acc[i][j] += (double)a[i] * (double)bb[j];
    }
    __syncthreads();
  }
#pragma unroll
  for (int i = 0; i < 4; i++) {
    int t = t0 + ty * 4 + i;
    if (t < 1000)
#pragma unroll
      for (int j = 0; j < 4; j++)
        g_encT[(size_t)t * 20480 + b * 640 + j0 + tx * 4 + j] =
            (float)(acc[i][j] + (double)bj[j0 + tx * 4 + j]);
  }
}

// ------------- precompute: packed f64 weights ------------------------------------
__global__ __launch_bounds__(256) void k_tr(const float* __restrict__ Wh,
                                            const float* __restrict__ Wpred,
                                            const float* __restrict__ Wout) {
  const int bid = blockIdx.x, tid = threadIdx.x;
  if (bid < 3200) {                 // g_Wg64: 64 ug x 50 cols
    int ug = bid / 50, cid = bid % 50;
    const int u0 = ug * 10;
    for (int k = tid; k < 640; k += 256) {
      double v;
      if (cid < 10) v = (double)Wpred[(size_t)k * 640 + u0 + cid];
      else {
        int gi = (cid - 10) / 10, ul = (cid - 10) % 10;
        v = (double)Wh[(size_t)k * 2560 + gi * 640 + u0 + ul];
      }
      g_Wg64[((size_t)ug * 50 + cid) * 640 + k] = v;
    }
  } else {                          // g_WoT64
    int cc = bid - 3200;            // < 1025
    for (int k = tid; k < 640; k += 256)
      g_WoT64[(size_t)cc * 640 + k] = (double)Wout[(size_t)k * 1025 + cc];
  }
}

// ------------------------------- persistent decode ------------------------------------
__global__ __launch_bounds__(256, 2) void k_decode(float* __restrict__ out,
                                                   const int* __restrict__ lens,
                                                   const float* __restrict__ b_out) {
  __shared__ __align__(16) float  hst[8 * 658];     // staged h / tanh (f32), swizzled
  __shared__ __align__(16) float  exA[320];         // [8][20][2] gate pre-acts
  __shared__ __align__(16) double exP[8 * 10 * 9];  // pred k-partials [r][j][ks pad9]
  __shared__ __align__(16) double exB2[8 * 40 * 9]; // spec k-partials [r][gcol][ks pad9]
  double* exO = exB2;                               // out role: [r][17][ks pad9]

  const int tid = threadIdx.x;
  const int bid = blockIdx.x;
  const int bloc = tid >> 5;        // local row 0..7 (32-lane row groups)
  const int c = tid & 31;
  const int wv = tid >> 6;          // wave 0..3
  const int lane = tid & 63;
  const int rr = lane >> 3;         // dot-phase row 0..7
  const int kss = lane & 7;         // dot-phase k-chunk 0..7
  const int hb = rr * 658 + kss * 82;

  if (bid < NGB) {
    // ========== GATE+PRED role: 10 units x 8 rows; XCD-pinned unit slice ==========
    const int xcd = bid & 7, slot = bid >> 3;
    const int ug = xcd * 8 + (slot & 7);   // 0..63
    const int rg = slot >> 3;              // 0..3
    const int u0 = ug * 10;
    const int b = rg * 8 + bloc;
    const int len_r = lens[b];
    const double* wgbase = g_Wg64 + (size_t)ug * 50 * 640;

    double GA0 = 0.0, GA1 = 0.0, ccur = 0.0;
    float hcur = 0.0f;
    int last_r = 1024;
    int alive = (0 < len_r) ? 1 : 0;
    int ti = 0, si = 0;

    for (int step = 0; step < 5000; step++) {
      // ---- phase A: gates = G + LUT[last]; pointwise -> h_new; publish ----
      float encf = 0.0f;
      if (c < 10) encf = g_encT[(size_t)ti * 20480 + b * 640 + u0 + c];
      const float* lrow = g_lutP + ((size_t)ug * 1025 + last_r) * 40;
      if (c < 20) {
        exA[(bloc * 20 + c) * 2 + 0] = (float)(GA0 + (double)lrow[c]);
        exA[(bloc * 20 + c) * 2 + 1] = (float)(GA1 + (double)lrow[20 + c]);
      }
      __syncthreads();
      double cn = 0.0; float hn = 0.0f;
      if (c < 10) {  // pt0 owner has (i,g); partner c+10 has (f,o)
        float fi = exA[(bloc * 20 + c) * 2 + 0];
        float fg = exA[(bloc * 20 + c) * 2 + 1];
        float ff = exA[(bloc * 20 + c + 10) * 2 + 0];
        float fo = exA[(bloc * 20 + c + 10) * 2 + 1];
        cn = (double)sigmf(ff) * ccur + (double)sigmf(fi) * (double)tanhf(fg);
        hn = sigmf(fo) * tanhf((float)cn);
        __hip_atomic_store(&g_hnew[(step & 1) * 20480 + b * 640 + u0 + c], hn,
                           __ATOMIC_RELAXED, __HIP_MEMORY_SCOPE_AGENT);
      }
      __syncthreads();  // vmcnt-drain: h stores at MALL before bump
      if (tid == 0) bump(F1L + (bid >> 4), F1R, step);
      waitc(F1R, (u32)(step + 1) * 16u);

      // ---- stage full h (f32, swizzled) for our 8 rows ----
      stage8f(g_hnew + (step & 1) * 20480 + rg * 5120, hst, tid);
      __syncthreads();

      // ---- pred dot: 10 j-cols, C=3/wave (clamped dups), lane=(r,ks) ----
      {
        const int c0p = (wv * 3 + 0 < 10) ? wv * 3 + 0 : 9;
        const int c1p = (wv * 3 + 1 < 10) ? wv * 3 + 1 : 9;
        const int c2p = (wv * 3 + 2 < 10) ? wv * 3 + 2 : 9;
        const double* w0 = wgbase + (size_t)c0p * 640 + kss * 80;
        const double* w1 = wgbase + (size_t)c1p * 640 + kss * 80;
        const double* w2 = wgbase + (size_t)c2p * 640 + kss * 80;
        double a0 = 0.0, a1 = 0.0, a2 = 0.0;
#pragma unroll 4
        for (int i = 0; i < 40; i++) {
          float2 hf = *(const float2*)&hst[hb + 2 * i];
          double hx = (double)hf.x, hy = (double)hf.y;
          double2 q0 = *(const double2*)(w0 + 2 * i);
          double2 q1 = *(const double2*)(w1 + 2 * i);
          double2 q2 = *(const double2*)(w2 + 2 * i);
          a0 = fma(hy, q0.y, fma(hx, q0.x, a0));
          a1 = fma(hy, q1.y, fma(hx, q1.x, a1));
          a2 = fma(hy, q2.y, fma(hx, q2.x, a2));
        }
        exP[(rr * 10 + c0p) * 9 + kss] = a0;  // dup writes carry equal values
        exP[(rr * 10 + c1p) * 9 + kss] = a1;
        exP[(rr * 10 + c2p) * 9 + kss] = a2;
      }
      __syncthreads();
      if (c < 10) {  // pred publish: sum 8 k-partials, add enc, tanh
        double tot = 0.0;
#pragma unroll
        for (int q = 0; q < 8; q++) tot += exP[(bloc * 10 + c) * 9 + q];
        float th = tanhf((float)((double)encf + tot));
        __hip_atomic_store(&g_tnh[b * 640 + u0 + c], th,
                           __ATOMIC_RELAXED, __HIP_MEMORY_SCOPE_AGENT);
      }
      __syncthreads();
      if (tid == 0) bump(F2L + (bid >> 4), F2R, step);

      // ---- spec dot: G_spec = h_new @ Wh, 40 cols, 2 passes x C=5 (overlaps out round)
#pragma unroll
      for (int p = 0; p < 2; p++) {
        const double* wb = wgbase + (size_t)(10 + wv * 10 + p * 5) * 640 + kss * 80;
        double ac0 = 0.0, ac1 = 0.0, ac2 = 0.0, ac3 = 0.0, ac4 = 0.0;
#pragma unroll 4
        for (int i = 0; i < 40; i++) {
          float2 hf = *(const float2*)&hst[hb + 2 * i];
          double hx = (double)hf.x, hy = (double)hf.y;
          double2 q0 = *(const double2*)(wb + 0 * 640 + 2 * i);
          double2 q1 = *(const double2*)(wb + 1 * 640 + 2 * i);
          double2 q2 = *(const double2*)(wb + 2 * 640 + 2 * i);
          double2 q3 = *(const double2*)(wb + 3 * 640 + 2 * i);
          double2 q4 = *(const double2*)(wb + 4 * 640 + 2 * i);
          ac0 = fma(hy, q0.y, fma(hx, q0.x, ac0));
          ac1 = fma(hy, q1.y, fma(hx, q1.x, ac1));
          ac2 = fma(hy, q2.y, fma(hx, q2.x, ac2));
          ac3 = fma(hy, q3.y, fma(hx, q3.x, ac3));
          ac4 = fma(hy, q4.y, fma(hx, q4.x, ac4));
        }
        const int cb = wv * 10 + p * 5;
        exB2[(rr * 40 + cb + 0) * 9 + kss] = ac0;
        exB2[(rr * 40 + cb + 1) * 9 + kss] = ac1;
        exB2[(rr * 40 + cb + 2) * 9 + kss] = ac2;
        exB2[(rr * 40 + cb + 3) * 9 + kss] = ac3;
        exB2[(rr * 40 + cb + 4) * 9 + kss] = ac4;
      }
      waitc(F3R, (u32)(step + 1) * 16u);  // also orders exB2 writes -> reads

      // ---- commit: gather G_spec, per-row argmax over 64 candidates ----
      double nGA0 = 0.0, nGA1 = 0.0;
      if (c < 20) {
#pragma unroll
        for (int q = 0; q < 8; q++) nGA0 += exB2[(bloc * 40 + c) * 9 + q];
#pragma unroll
        for (int q = 0; q < 8; q++) nGA1 += exB2[(bloc * 40 + 20 + c) * 9 + q];
      }
      u64 v1b = __hip_atomic_load(&g_cval[b * 64 + c], __ATOMIC_RELAXED, __HIP_MEMORY_SCOPE_AGENT);
      int  i1  = __hip_atomic_load(&g_cidx[b * 64 + c], __ATOMIC_RELAXED, __HIP_MEMORY_SCOPE_AGENT);
      u64 v2b = __hip_atomic_load(&g_cval[b * 64 + c + 32], __ATOMIC_RELAXED, __HIP_MEMORY_SCOPE_AGENT);
      int  i2  = __hip_atomic_load(&g_cidx[b * 64 + c + 32], __ATOMIC_RELAXED, __HIP_MEMORY_SCOPE_AGENT);
      double bv = __longlong_as_double((long long)v1b); int bi = i1;
      double v2 = __longlong_as_double((long long)v2b);
      if (v2 > bv || (v2 == bv && i2 < bi)) { bv = v2; bi = i2; }
#pragma unroll
      for (int m = 1; m < 32; m <<= 1) {   // reduce within the 32-lane row group
        double vv = __shfl_xor(bv, m, 64);
        int ii = __shfl_xor(bi, m, 64);
        if (vv > bv || (vv == bv && ii < bi)) { bv = vv; bi = ii; }
      }
      int sym = bi;
      int em = (alive && sym != 1024) ? 1 : 0;
      if (ug == 0 && c == 0)
        out[(size_t)b * 5000 + step] = (float)(em ? sym : 1024);
      if (em) {
        last_r = sym;
        if (c < 20) { GA0 = nGA0; GA1 = nGA1; }
        if (c < 10) { ccur = cn; hcur = hn; }
      }
      alive = (si == 4) ? ((ti + 1 < len_r) ? 1 : 0) : em;
      si++; if (si == 5) { si = 0; ti++; }
    }
    if (c < 10) {  // cache_rnn_state = stack([h, c])
      out[160000 + b * 640 + u0 + c] = hcur;
      out[160000 + 20480 + b * 640 + u0 + c] = (float)ccur;
    }

  } else {
    // ========== OUT role: 16(+blank) Wout cols x 8 rows; XCD-pinned ==========
    const int o = bid - NGB;
    const int xcd = o & 7, slot = o >> 3;
    const int cg = xcd * 8 + (slot & 7);   // 0..63
    const int rg = slot >> 3;              // 0..3
    const int b = rg * 8 + bloc;
    const bool blkrole = (cg == 63);       // owns blank col 1024 as local col 16
    const int ncols = blkrole ? 17 : 16;
    // per-wave cols (C=5, clamped dups): cidc = min(wv*5+cc, ncols-1)
    int cid0 = wv * 5 + 0, cid1 = wv * 5 + 1, cid2 = wv * 5 + 2,
        cid3 = wv * 5 + 3, cid4 = wv * 5 + 4;
    cid0 = (cid0 < ncols) ? cid0 : ncols - 1;
    cid1 = (cid1 < ncols) ? cid1 : ncols - 1;
    cid2 = (cid2 < ncols) ? cid2 : ncols - 1;
    cid3 = (cid3 < ncols) ? cid3 : ncols - 1;
    cid4 = (cid4 < ncols) ? cid4 : ncols - 1;
    const int gc0 = (cid0 < 16) ? cg * 16 + cid0 : 1024;
    const int gc1 = (cid1 < 16) ? cg * 16 + cid1 : 1024;
    const int gc2 = (cid2 < 16) ? cg * 16 + cid2 : 1024;
    const int gc3 = (cid3 < 16) ? cg * 16 + cid3 : 1024;
    const int gc4 = (cid4 < 16) ? cg * 16 + cid4 : 1024;
    const double* w0 = g_WoT64 + (size_t)gc0 * 640 + kss * 80;
    const double* w1 = g_WoT64 + (size_t)gc1 * 640 + kss * 80;
    const double* w2 = g_WoT64 + (size_t)gc2 * 640 + kss * 80;
    const double* w3 = g_WoT64 + (size_t)gc3 * 640 + kss * 80;
    const double* w4 = g_WoT64 + (size_t)gc4 * 640 + kss * 80;
    // reduce-phase constants (thread (bloc, c<17))
    const int rcol = (c < 16) ? cg * 16 + c : 1024;
    const double bo_c = (c < 17) ? (double)b_out[rcol] : 0.0;

    for (int step = 0; step < 5000; step++) {
      waitc(F2R, (u32)(step + 1) * 16u);
      stage8f(g_tnh + rg * 5120, hst, tid);
      __syncthreads();
      {
        double a0 = 0.0, a1 = 0.0, a2 = 0.0, a3 = 0.0, a4 = 0.0;
#pragma unroll 4
        for (int i = 0; i < 40; i++) {
          float2 hf = *(const float2*)&hst[hb + 2 * i];
          double hx = (double)hf.x, hy = (double)hf.y;
          double2 q0 = *(const double2*)(w0 + 2 * i);
          double2 q1 = *(const double2*)(w1 + 2 * i);
          double2 q2 = *(const double2*)(w2 + 2 * i);
          double2 q3 = *(const double2*)(w3 + 2 * i);
          double2 q4 = *(const double2*)(w4 + 2 * i);
          a0 = fma(hy, q0.y, fma(hx, q0.x, a0));
          a1 = fma(hy, q1.y, fma(hx, q1.x, a1));
          a2 = fma(hy, q2.y, fma(hx, q2.x, a2));
          a3 = fma(hy, q3.y, fma(hx, q3.x, a3));
          a4 = fma(hy, q4.y, fma(hx, q4.x, a4));
        }
        exO[(rr * 17 + cid0) * 9 + kss] = a0;  // dup writes carry equal values
        exO[(rr * 17 + cid1) * 9 + kss] = a1;
        exO[(rr * 17 + cid2) * 9 + kss] = a2;
        exO[(rr * 17 + cid3) * 9 + kss] = a3;
        exO[(rr * 17 + cid4) * 9 + kss] = a4;
      }
      __syncthreads();
      // per-row argmax over this block's cols; publish candidate
      double bv = -1.0e300; int bi = 0x7fffffff;
      if (c < ncols) {
        double lg = bo_c;
#pragma unroll
        for (int q = 0; q < 8; q++) lg += exO[(bloc * 17 + c) * 9 + q];
        bv = lg; bi = rcol;
      }
#pragma unroll
      for (int m = 1; m < 32; m <<= 1) {
        double vv = __shfl_xor(bv, m, 64);
        int ii = __shfl_xor(bi, m, 64);
        if (vv > bv || (vv == bv && ii < bi)) { bv = vv; bi = ii; }
      }
      if (c == 0) {
        __hip_atomic_store(&g_cval[b * 64 + cg], (u64)__double_as_longlong(bv),
                           __ATOMIC_RELAXED, __HIP_MEMORY_SCOPE_AGENT);
        __hip_atomic_store(&g_cidx[b * 64 + cg], bi,
                           __ATOMIC_RELAXED, __HIP_MEMORY_SCOPE_AGENT);
      }
      __syncthreads();  // vmcnt-drain before bump
      if (tid == 0) bump(F3L + (o >> 4), F3R, step);
    }
  }
}

extern "C" void kernel_launch(void* const* d_in, const int* in_sizes, int n_in,
                              void* d_out, int out_size, void* d_ws, size_t ws_size,
                              hipStream_t stream) {
  const float* enc = (const float*)d_in[0];
  const int* lens = (const int*)d_in[1];
  const float* embed = (const float*)d_in[2];
  const float* Wx = (const float*)d_in[3];
  const float* Wh = (const float*)d_in[4];
  const float* b_lstm = (const float*)d_in[5];
  const float* Wenc = (const float*)d_in[6];
  const float* Wpred = (const float*)d_in[7];
  const float* b_joint = (const float*)d_in[8];
  const float* Wout = (const float*)d_in[9];
  const float* b_out = (const float*)d_in[10];
  float* out = (float*)d_out;
  (void)d_ws; (void)ws_size; (void)in_sizes; (void)n_in; (void)out_size;

  hipLaunchKernelGGL(k_lut, dim3(1290), dim3(256), 0, stream, embed, Wx, b_lstm);
  hipLaunchKernelGGL(k_encproj, dim3(160, 32), dim3(256), 0, stream, enc, Wenc, b_joint);
  hipLaunchKernelGGL(k_tr, dim3(4225), dim3(256), 0, stream, Wh, Wpred, Wout);
  hipLaunchKernelGGL(k_decode, dim3(NBLK), dim3(256), 0, stream, out, lens, b_out);
}

// Round 5
// 211274.805 us; speedup vs baseline: 2.1306x; 2.1306x over previous
//
#include <hip/hip_runtime.h>
#include <stdint.h>

// RNN-T greedy decode v7 = v2 (verified 200ms) minus the F4 argmax round.
//
// Session ledger: v2 (4 rounds, agent fences + cached loads, weights in LDS)
// = 200ms PASS. v3-v5 (all-MALL atomic transport) = 344/414/450ms PASS.
// v6 (unverified sc0/sc1 mailbox protocol) = FAIL (watchdog abort).
// Lessons: (1) fence+cached is the fastest verified transport; (2) never
// build sync on unmeasured cache-bit semantics; (3) compute is NOT the
// bottleneck (VALU <17% everywhere) — device-wide rounds are.
//
// v7 delta vs v2 (only this): out blocks + blank owner publish 129
// candidates (F3, verbatim); gate blocks then REDUNDANTLY argmax-reduce the
// 129 candidates per row (cached loads after F3 acquire + 8-lane shfl
// butterfly) and keep last/alive per-row in registers. The F4 round, the
// pred-side LDS argmax tree (source of the 1.03e9 bank conflicts), and the
// g_last/g_emit coherence hops are deleted. 4 rounds/step -> 3.

typedef unsigned int u32;

constexpr int NGB = 160, NPB = 160, NOB = 128, NBLK = NGB + NPB + NOB; // 448
constexpr int LDSTR = 648; // padded LDS row stride (2-way bank alias only = free)

// ---- static device scratch ----
__device__ float  g_encT[1000 * 32 * 640];   // enc@Wenc + b_joint, [T][B][J]
__device__ float  g_lut[1025 * 2560];        // embed@Wx + b_lstm (row 1024 = b_lstm)
__device__ float  g_hnew[2 * 32 * 640];      // double-buffered by step parity
__device__ float  g_tnh[32 * 640];           // tanh(joint pre-act)
__device__ double g_cval[32 * 132];          // argmax candidate values
__device__ int    g_cidx[32 * 132];          // argmax candidate indices
__device__ u32    g_cnt[64 * 32];            // counters, 128 B apart

// counter slot indices (each slot = 32 u32 = 128 B)
constexpr int F1L = 0,  F1R = 10;  // 10 leaves x16 gate blocks
constexpr int F2L = 11, F2R = 21;  // 10 leaves x16 pred blocks
constexpr int F3L = 22, F3R = 30;  // 8 leaves x16 out blocks + 1 direct (9/step)

__device__ __forceinline__ float sigmf(float x) { return 1.0f / (1.0f + expf(-x)); }

__device__ __forceinline__ void bump(int leaf, int root, int step) {
  // caller: thread 0, after __syncthreads() (all waves' stores vmcnt-drained)
  __builtin_amdgcn_fence(__ATOMIC_RELEASE, "agent");
  u32 old = __hip_atomic_fetch_add(&g_cnt[leaf * 32], 1u, __ATOMIC_RELAXED, __HIP_MEMORY_SCOPE_AGENT);
  if (old + 1u == (u32)(step + 1) * 16u)
    __hip_atomic_fetch_add(&g_cnt[root * 32], 1u, __ATOMIC_RELAXED, __HIP_MEMORY_SCOPE_AGENT);
}

__device__ __forceinline__ void waitc(int root, u32 target) {
  if (threadIdx.x == 0) {
    while (__hip_atomic_load(&g_cnt[root * 32], __ATOMIC_RELAXED, __HIP_MEMORY_SCOPE_AGENT) < target)
      __builtin_amdgcn_s_sleep(1);
    __builtin_amdgcn_fence(__ATOMIC_ACQUIRE, "agent");  // invalidate stale cache lines
  }
  __syncthreads();
}

// ---------------- precompute: LUT = embed @ Wx + b_lstm (row 1024 = b_lstm) -----------
__global__ __launch_bounds__(256) void k_lut(const float* __restrict__ embed,
                                             const float* __restrict__ Wx,
                                             const float* __restrict__ b_lstm) {
  const int tid = threadIdx.x;
  const int cg = blockIdx.x % 10, rg = blockIdx.x / 10;  // rg 0..128
  const int c = cg * 256 + tid;
  const int r0 = rg * 8;
  double acc[8];
  double bl = (double)b_lstm[c];
#pragma unroll
  for (int i = 0; i < 8; i++) acc[i] = bl;
  for (int e = 0; e < 640; e++) {
    double wx = (double)Wx[(size_t)e * 2560 + c];
#pragma unroll
    for (int i = 0; i < 8; i++) {
      int r = r0 + i;
      if (r < 1024) acc[i] += (double)embed[(size_t)r * 640 + e] * wx;
    }
  }
#pragma unroll
  for (int i = 0; i < 8; i++) {
    int r = r0 + i;
    if (r < 1025) g_lut[(size_t)r * 2560 + c] = (float)acc[i];
  }
  if (blockIdx.x == 0) {  // init counters every call (graph replay safe)
    for (int i = tid; i < 64 * 32; i += 256) g_cnt[i] = 0u;
  }
}

// ------------- precompute: encT[t][b][j] = sum_d enc[b][d][t]*Wenc[d][j] + b_joint[j] --
__global__ __launch_bounds__(256) void k_encproj(const float* __restrict__ enc,
                                                 const float* __restrict__ Wenc,
                                                 const float* __restrict__ bj) {
  __shared__ __align__(16) float As[16][68];
  __shared__ __align__(16) float Bs[16][68];
  const int tid = threadIdx.x;
  const int jt = blockIdx.x % 10, tt = blockIdx.x / 10;  // 10 j-tiles, 16 t-tiles
  const int b = blockIdx.y;
  const int t0 = tt * 64, j0 = jt * 64;
  const int ty = tid >> 4, tx = tid & 15;
  double acc[4][4] = {};
  const float* Ab = enc + (size_t)b * 640 * 1000;
  for (int d0 = 0; d0 < 640; d0 += 16) {
#pragma unroll
    for (int i = 0; i < 4; i++) {
      int idx = tid + i * 256;
      int d = idx >> 6, t = idx & 63;
      As[d][t] = (t0 + t < 1000) ? Ab[(size_t)(d0 + d) * 1000 + t0 + t] : 0.f;
      Bs[d][t] = Wenc[(size_t)(d0 + d) * 640 + j0 + t];
    }
    __syncthreads();
#pragma unroll
    for (int kk = 0; kk < 16; kk++) {
      float4 av = *(const float4*)&As[kk][ty * 4];
      float4 bv = *(const float4*)&Bs[kk][tx * 4];
      float a[4] = {av.x, av.y, av.z, av.w};
      float bb[4] = {bv.x, bv.y, bv.z, bv.w};
#pragma unroll
      for (int i = 0; i < 4; i++)
#pragma unroll
        for (int j = 0; j < 4; j++) acc[i][j] += (double)a[i] * (double)bb[j];
    }
    __syncthreads();
  }
#pragma unroll
  for (int i = 0; i < 4; i++) {
    int t = t0 + ty * 4 + i;
    if (t < 1000)
#pragma unroll
      for (int j = 0; j < 4; j++)
        g_encT[(size_t)t * 20480 + b * 640 + j0 + tx * 4 + j] =
            (float)(acc[i][j] + (double)bj[j0 + tx * 4 + j]);
  }
}

// ------------------------------- persistent decode ------------------------------------
__global__ __launch_bounds__(256, 2) void k_decode(float* __restrict__ out,
                                                   const int* __restrict__ lens,
                                                   const float* __restrict__ Wh,
                                                   const float* __restrict__ Wpred,
                                                   const float* __restrict__ Wout,
                                                   const float* __restrict__ b_out) {
  __shared__ __align__(16) float wsl[16 * LDSTR];  // weight slice (role-dependent)

  const int tid = threadIdx.x;
  const int bid = blockIdx.x;

  if (bid < NGB) {
    // ================= GATE role: 4 units each; 16 Wh cols in LDS ==================
    const int b = tid >> 3, c0 = tid & 7;
    const int u0 = bid * 4;
    for (int idx = tid; idx < 16 * 640; idx += 256) {
      int ci = idx / 640, k = idx - ci * 640;
      int g = ci >> 2, ul = ci & 3;
      wsl[ci * LDSTR + k] = Wh[(size_t)k * 2560 + g * 640 + u0 + ul];
    }
    __syncthreads();
    // thread (b,c0): gate cols ci=c0 (g=c0>>2 in {i,f}) and ci=c0+8 (g+2 in {g,o})
    const int g1 = c0 >> 2, ul = c0 & 3;
    const int col1 = g1 * 640 + u0 + ul;
    const int col2 = col1 + 1280;
    double G1 = 0.0, G2 = 0.0, ccur = 0.0;  // invariant: G = h_committed @ Wh
    float hcur = 0.f;
    const float* w1 = &wsl[c0 * LDSTR];
    const float* w2 = &wsl[(c0 + 8) * LDSTR];
    // per-row decode state, tracked redundantly by all gate blocks (v7)
    const int len_r = lens[b];
    int last_b = 1024;
    int alive = (0 < len_r) ? 1 : 0;
    int ti = 0, si = 0;

    for (int step = 0; step < 5000; step++) {
      // --- phase A: finish gates with LUT[last], pointwise, publish h_new ---
      const float* lrow = g_lut + (size_t)last_b * 2560;
      double gate1 = G1 + (double)lrow[col1];
      double gate2 = G2 + (double)lrow[col2];
      double x1 = __shfl_xor(gate1, 4, 64);  // partner has (f,o)
      double x2 = __shfl_xor(gate2, 4, 64);
      double cn = 0.0; float hn = 0.f;
      if (c0 < 4) {
        float fi = (float)gate1, fg = (float)gate2, ff = (float)x1, fo = (float)x2;
        cn = (double)sigmf(ff) * ccur + (double)sigmf(fi) * (double)tanhf(fg);
        hn = sigmf(fo) * tanhf((float)cn);
        g_hnew[(step & 1) * 20480 + b * 640 + u0 + c0] = hn;
      }
      __syncthreads();
      if (tid == 0) bump(F1L + (bid >> 4), F1R, step);
      // --- phase B: speculative G_spec = h_new @ Wh (overlaps joint path) ---
      waitc(F1R, (u32)(step + 1) * 10u);
      const float* hb = g_hnew + (step & 1) * 20480 + b * 640;
      double a1 = 0.0, a2 = 0.0;
      for (int k = 0; k < 640; k += 4) {
        float4 h4 = *(const float4*)(hb + k);
        float4 q1 = *(const float4*)(w1 + k);
        float4 q2 = *(const float4*)(w2 + k);
        a1 += (double)h4.x * q1.x; a1 += (double)h4.y * q1.y;
        a1 += (double)h4.z * q1.z; a1 += (double)h4.w * q1.w;
        a2 += (double)h4.x * q2.x; a2 += (double)h4.y * q2.y;
        a2 += (double)h4.z * q2.z; a2 += (double)h4.w * q2.w;
      }
      // --- phase C: wait candidates, redundant per-row argmax, commit ---
      waitc(F3R, (u32)(step + 1) * 9u);
      double bv = -1.0e300; int bi = 0x7fffffff;
#pragma unroll 4
      for (int k2 = 0; k2 < 16; k2++) {  // lane c0 scans slots c0+8k (cached loads)
        int slot = c0 + 8 * k2;
        double v = g_cval[b * 132 + slot];
        int ii = g_cidx[b * 132 + slot];
        if (v > bv || (v == bv && ii < bi)) { bv = v; bi = ii; }
      }
      if (c0 == 0) {  // blank candidate, slot 128
        double v = g_cval[b * 132 + 128];
        int ii = g_cidx[b * 132 + 128];
        if (v > bv || (v == bv && ii < bi)) { bv = v; bi = ii; }
      }
#pragma unroll
      for (int m = 1; m < 8; m <<= 1) {  // butterfly within the 8-lane row group
        double vv = __shfl_xor(bv, m, 64);
        int ii = __shfl_xor(bi, m, 64);
        if (vv > bv || (vv == bv && ii < bi)) { bv = vv; bi = ii; }
      }
      int sym = bi;
      int em = (alive && sym != 1024) ? 1 : 0;
      if (bid == 0 && c0 == 0)
        out[(size_t)b * 5000 + step] = (float)(em ? sym : 1024);
      if (em) {
        last_b = sym;
        G1 = a1; G2 = a2;
        if (c0 < 4) { ccur = cn; hcur = hn; }
      }
      alive = (si == 4) ? ((ti + 1 < len_r) ? 1 : 0) : em;
      si++; if (si == 5) { si = 0; ti++; }
    }
    if (c0 < 4) {  // cache_rnn_state = stack([h, c])
      out[160000 + b * 640 + u0 + c0] = hcur;
      out[160000 + 20480 + b * 640 + u0 + c0] = (float)ccur;
    }

  } else if (bid < NGB + NPB) {
    // ========== PRED role: 4 Wpred cols each (split-k x2); p==32 owns blank =========
    const int p = bid - NGB;  // 0..159
    const int b = tid >> 3, c2 = tid & 7;
    const int cl = c2 >> 1, half = c2 & 1;
    const int j = p * 4 + cl;
    for (int idx = tid; idx < 4 * 640; idx += 256) {
      int ci = idx / 640, k = idx - ci * 640;
      wsl[ci * LDSTR + k] = Wpred[(size_t)k * 640 + p * 4 + ci];
    }
    if (p == 32) {  // blank-column owner: Wout[:,1024] in slot 4
      for (int idx = tid; idx < 640; idx += 256)
        wsl[4 * LDSTR + idx] = Wout[(size_t)idx * 1025 + 1024];
    }
    __syncthreads();
    const double bo1024 = (double)b_out[1024];
    int t = 0, s = 0;

    for (int step = 0; step < 5000; step++) {
      waitc(F1R, (u32)(step + 1) * 10u);
      const float* hb = g_hnew + (step & 1) * 20480 + b * 640 + half * 320;
      const float* wv = &wsl[cl * LDSTR + half * 320];
      double a = 0.0;
      for (int k = 0; k < 320; k += 4) {
        float4 h4 = *(const float4*)(hb + k);
        float4 q = *(const float4*)(wv + k);
        a += (double)h4.x * q.x; a += (double)h4.y * q.y;
        a += (double)h4.z * q.z; a += (double)h4.w * q.w;
      }
      a += __shfl_xor(a, 1, 64);
      if (half == 0) {
        double pre = (double)g_encT[(size_t)t * 20480 + b * 640 + j] + a;
        g_tnh[b * 640 + j] = tanhf((float)pre);
      }
      __syncthreads();
      if (tid == 0) bump(F2L + (p >> 4), F2R, step);

      if (p == 32) {  // blank logit: 8 lanes x 80 k per row; publish slot 128
        waitc(F2R, (u32)(step + 1) * 10u);
        const float* tb = g_tnh + b * 640 + c2 * 80;
        const float* wv2 = &wsl[4 * LDSTR + c2 * 80];
        double a2 = 0.0;
        for (int k = 0; k < 80; k += 4) {
          float4 t4 = *(const float4*)(tb + k);
          float4 q = *(const float4*)(wv2 + k);
          a2 += (double)t4.x * q.x; a2 += (double)t4.y * q.y;
          a2 += (double)t4.z * q.z; a2 += (double)t4.w * q.w;
        }
        a2 += __shfl_xor(a2, 1, 64);
        a2 += __shfl_xor(a2, 2, 64);
        a2 += __shfl_xor(a2, 4, 64);
        if (c2 == 0) { g_cval[b * 132 + 128] = a2 + bo1024; g_cidx[b * 132 + 128] = 1024; }
        __syncthreads();
        if (tid == 0) {
          __builtin_amdgcn_fence(__ATOMIC_RELEASE, "agent");
          __hip_atomic_fetch_add(&g_cnt[F3R * 32], 1u, __ATOMIC_RELAXED, __HIP_MEMORY_SCOPE_AGENT);
        }
      }
      s++; if (s == 5) { s = 0; t++; }
    }

  } else {
    // ================= OUT role: 8 Wout cols each ==================================
    const int o = bid - NGB - NPB;  // 0..127
    const int b = tid >> 3, c = tid & 7;
    const int col = o * 8 + c;  // <= 1023
    for (int idx = tid; idx < 8 * 640; idx += 256) {
      int ci = idx / 640, k = idx - ci * 640;
      wsl[ci * LDSTR + k] = Wout[(size_t)k * 1025 + o * 8 + ci];
    }
    __syncthreads();
    const double bo = (double)b_out[col];
    const float* wv = &wsl[c * LDSTR];

    for (int step = 0; step < 5000; step++) {
      waitc(F2R, (u32)(step + 1) * 10u);
      const float* tb = g_tnh + b * 640;
      double a = bo;
      for (int k = 0; k < 640; k += 4) {
        float4 t4 = *(const float4*)(tb + k);
        float4 q = *(const float4*)(wv + k);
        a += (double)t4.x * q.x; a += (double)t4.y * q.y;
        a += (double)t4.z * q.z; a += (double)t4.w * q.w;
      }
      double bv = a; int bi = col;
#pragma unroll
      for (int m = 1; m < 8; m <<= 1) {  // argmax over the 8 cols of this block
        double v2 = __shfl_xor(bv, m, 64);
        int i2 = __shfl_xor(bi, m, 64);
        if (v2 > bv || (v2 == bv && i2 < bi)) { bv = v2; bi = i2; }
      }
      if (c == 0) { g_cval[b * 132 + o] = bv; g_cidx[b * 132 + o] = bi; }
      __syncthreads();
      if (tid == 0) bump(F3L + (o >> 4), F3R, step);
    }
  }
}

extern "C" void kernel_launch(void* const* d_in, const int* in_sizes, int n_in,
                              void* d_out, int out_size, void* d_ws, size_t ws_size,
                              hipStream_t stream) {
  const float* enc = (const float*)d_in[0];
  const int* lens = (const int*)d_in[1];
  const float* embed = (const float*)d_in[2];
  const float* Wx = (const float*)d_in[3];
  const float* Wh = (const float*)d_in[4];
  const float* b_lstm = (const float*)d_in[5];
  const float* Wenc = (const float*)d_in[6];
  const float* Wpred = (const float*)d_in[7];
  const float* b_joint = (const float*)d_in[8];
  const float* Wout = (const float*)d_in[9];
  const float* b_out = (const float*)d_in[10];
  float* out = (float*)d_out;
  (void)d_ws; (void)ws_size; (void)in_sizes; (void)n_in; (void)out_size;

  hipLaunchKernelGGL(k_lut, dim3(1290), dim3(256), 0, stream, embed, Wx, b_lstm);
  hipLaunchKernelGGL(k_encproj, dim3(160, 32), dim3(256), 0, stream, enc, Wenc, b_joint);
  hipLaunchKernelGGL(k_decode, dim3(NBLK), dim3(256), 0, stream,
                     out, lens, Wh, Wpred, Wout, b_out);
}

// Round 6
// 200903.271 us; speedup vs baseline: 2.2406x; 1.0516x over previous
//
#include <hip/hip_runtime.h>
#include <stdint.h>

// RNN-T greedy decode v8 — MALL-traffic-minimized 4-round pipeline.
//
// Session ledger: v2 4-round fence+cached = 200ms; v7 (3-round, +8MB/step
// redundant cand reads) = 211ms; v3-v5 (all-MALL transport, 30-50MB/step
// uncached) = 344-450ms; v6 (unverified sc0 protocol) = FAIL.
// Model that fits all points: step time ~ post-acquire MALL refill bytes
// (consumers x bytes), NOT round count. Rounds with tiny consumer sets
// (v2's F4) are ~free.
//
// v8 deltas (all verified mechanisms, recombined):
//  * Merge pred INTO gate -> GP role (160 blocks): Wh 16 cols + Wpred 4 cols
//    in LDS (51.8KB, 2/CU safe); h consumed by 160 blocks instead of 320
//    (h refill 25.6 -> 12.8 MB/step).
//  * Candidates: v2-style owner reduce (32 GP blocks, shfl butterfly over
//    129 slots, publish last/emit ~256B) instead of v7's 160-block
//    redundant read (8 -> 1.6 MB/step). F4 round restored (~free).
//  * Blank column = 129th out block with clamped cols (v5-verified trick);
//    pred blank stage gone.
//  * 289 blocks total: CU-doubling 192 -> ~33 CUs (fewer stragglers).

typedef unsigned int u32;

constexpr int NGB = 160;              // GP (gate+pred) blocks
constexpr int NOB = 129;              // out blocks (128 x 8 cols + blank block)
constexpr int NBLK = NGB + NOB;       // 289
constexpr int LDSTR = 648;            // padded LDS row stride (2-way alias = free)

// ---- static device scratch ----
__device__ float  g_encT[1000 * 32 * 640];   // enc@Wenc + b_joint, [T][B][J]
__device__ float  g_lut[1025 * 2560];        // embed@Wx + b_lstm (row 1024 = b_lstm)
__device__ float  g_hnew[2 * 32 * 640];      // double-buffered by step parity
__device__ float  g_tnh[32 * 640];           // tanh(joint pre-act)
__device__ double g_cval[32 * 132];          // candidate values (slots 0..128)
__device__ int    g_cidx[32 * 132];          // candidate indices
__device__ int    g_last[32];
__device__ int    g_emit[32];
__device__ u32    g_cnt[64 * 32];            // counters, 128 B apart

// counter slots (each = 32 u32 = 128 B)
constexpr int F1L = 0,  F1R = 10;  // 10 leaves x16 GP blocks   (target *10)
constexpr int F2L = 11, F2R = 21;  // 10 leaves x16 GP blocks   (target *10)
constexpr int F3L = 22, F3R = 30;  // 8 leaves x16 out + 1 direct (target *9)
constexpr int F4L = 31, F4R = 33;  // 2 leaves x16 owners       (target *2)

__device__ __forceinline__ float sigmf(float x) { return 1.0f / (1.0f + expf(-x)); }

__device__ __forceinline__ void bump(int leaf, int root, int step) {
  // caller: thread 0 after __syncthreads() (all waves' stores vmcnt-drained)
  __builtin_amdgcn_fence(__ATOMIC_RELEASE, "agent");
  u32 old = __hip_atomic_fetch_add(&g_cnt[leaf * 32], 1u, __ATOMIC_RELAXED, __HIP_MEMORY_SCOPE_AGENT);
  if (old + 1u == (u32)(step + 1) * 16u)
    __hip_atomic_fetch_add(&g_cnt[root * 32], 1u, __ATOMIC_RELAXED, __HIP_MEMORY_SCOPE_AGENT);
}

__device__ __forceinline__ void waitc(int root, u32 target) {
  if (threadIdx.x == 0) {
    while (__hip_atomic_load(&g_cnt[root * 32], __ATOMIC_RELAXED, __HIP_MEMORY_SCOPE_AGENT) < target)
      __builtin_amdgcn_s_sleep(1);
    __builtin_amdgcn_fence(__ATOMIC_ACQUIRE, "agent");  // invalidate stale cache lines
  }
  __syncthreads();
}

// ---------------- precompute: LUT = embed @ Wx + b_lstm (row 1024 = b_lstm) -----------
__global__ __launch_bounds__(256) void k_lut(const float* __restrict__ embed,
                                             const float* __restrict__ Wx,
                                             const float* __restrict__ b_lstm) {
  const int tid = threadIdx.x;
  const int cg = blockIdx.x % 10, rg = blockIdx.x / 10;  // rg 0..128
  const int c = cg * 256 + tid;
  const int r0 = rg * 8;
  double acc[8];
  double bl = (double)b_lstm[c];
#pragma unroll
  for (int i = 0; i < 8; i++) acc[i] = bl;
  for (int e = 0; e < 640; e++) {
    double wx = (double)Wx[(size_t)e * 2560 + c];
#pragma unroll
    for (int i = 0; i < 8; i++) {
      int r = r0 + i;
      if (r < 1024) acc[i] += (double)embed[(size_t)r * 640 + e] * wx;
    }
  }
#pragma unroll
  for (int i = 0; i < 8; i++) {
    int r = r0 + i;
    if (r < 1025) g_lut[(size_t)r * 2560 + c] = (float)acc[i];
  }
  if (blockIdx.x == 0) {  // init sync state every call (graph replay safe)
    for (int i = tid; i < 64 * 32; i += 256) g_cnt[i] = 0u;
    if (tid < 32) { g_last[tid] = 1024; g_emit[tid] = 0; }
  }
}

// ------------- precompute: encT[t][b][j] = sum_d enc[b][d][t]*Wenc[d][j] + b_joint[j] --
__global__ __launch_bounds__(256) void k_encproj(const float* __restrict__ enc,
                                                 const float* __restrict__ Wenc,
                                                 const float* __restrict__ bj) {
  __shared__ __align__(16) float As[16][68];
  __shared__ __align__(16) float Bs[16][68];
  const int tid = threadIdx.x;
  const int jt = blockIdx.x % 10, tt = blockIdx.x / 10;  // 10 j-tiles, 16 t-tiles
  const int b = blockIdx.y;
  const int t0 = tt * 64, j0 = jt * 64;
  const int ty = tid >> 4, tx = tid & 15;
  double acc[4][4] = {};
  const float* Ab = enc + (size_t)b * 640 * 1000;
  for (int d0 = 0; d0 < 640; d0 += 16) {
#pragma unroll
    for (int i = 0; i < 4; i++) {
      int idx = tid + i * 256;
      int d = idx >> 6, t = idx & 63;
      As[d][t] = (t0 + t < 1000) ? Ab[(size_t)(d0 + d) * 1000 + t0 + t] : 0.f;
      Bs[d][t] = Wenc[(size_t)(d0 + d) * 640 + j0 + t];
    }
    __syncthreads();
#pragma unroll
    for (int kk = 0; kk < 16; kk++) {
      float4 av = *(const float4*)&As[kk][ty * 4];
      float4 bv = *(const float4*)&Bs[kk][tx * 4];
      float a[4] = {av.x, av.y, av.z, av.w};
      float bb[4] = {bv.x, bv.y, bv.z, bv.w};
#pragma unroll
      for (int i = 0; i < 4; i++)
#pragma unroll
        for (int j = 0; j < 4; j++) acc[i][j] += (double)a[i] * (double)bb[j];
    }
    __syncthreads();
  }
#pragma unroll
  for (int i = 0; i < 4; i++) {
    int t = t0 + ty * 4 + i;
    if (t < 1000)
#pragma unroll
      for (int j = 0; j < 4; j++)
        g_encT[(size_t)t * 20480 + b * 640 + j0 + tx * 4 + j] =
            (float)(acc[i][j] + (double)bj[j0 + tx * 4 + j]);
  }
}

// ------------------------------- persistent decode ------------------------------------
__global__ __launch_bounds__(256, 2) void k_decode(float* __restrict__ out,
                                                   const int* __restrict__ lens,
                                                   const float* __restrict__ Wh,
                                                   const float* __restrict__ Wpred,
                                                   const float* __restrict__ Wout,
                                                   const float* __restrict__ b_out) {
  __shared__ __align__(16) float wsl[20 * LDSTR];  // GP: 16 Wh cols + 4 Wpred cols

  const int tid = threadIdx.x;
  const int bid = blockIdx.x;

  if (bid < NGB) {
    // ============ GP role: gates for 4 units + pred for 4 j-cols ============
    const int b = tid >> 3, c0 = tid & 7;
    const int u0 = bid * 4;                    // unit base == pred col base
    for (int idx = tid; idx < 16 * 640; idx += 256) {
      int ci = idx / 640, k = idx - ci * 640;
      int g = ci >> 2, ul = ci & 3;
      wsl[ci * LDSTR + k] = Wh[(size_t)k * 2560 + g * 640 + u0 + ul];
    }
    for (int idx = tid; idx < 4 * 640; idx += 256) {
      int ci = idx / 640, k = idx - ci * 640;
      wsl[(16 + ci) * LDSTR + k] = Wpred[(size_t)k * 640 + u0 + ci];
    }
    __syncthreads();
    // gate thread (b,c0): cols ci=c0 (i/f) and ci=c0+8 (g/o)
    const int g1 = c0 >> 2, ul = c0 & 3;
    const int col1 = g1 * 640 + u0 + ul;
    const int col2 = col1 + 1280;
    const float* w1 = &wsl[c0 * LDSTR];
    const float* w2 = &wsl[(c0 + 8) * LDSTR];
    // pred thread (b,c0): col cl=c0>>1, k-half=c0&1
    const int cl = c0 >> 1, half = c0 & 1;
    const int j = u0 + cl;
    const float* wp = &wsl[(16 + cl) * LDSTR + half * 320];

    double G1 = 0.0, G2 = 0.0, ccur = 0.0;  // invariant: G = h_committed @ Wh
    float hcur = 0.f;
    // owner state (blocks 0..31 own row==bid's argmax; only tid 0's copy used)
    const bool owner = (bid < 32);
    const int len_o = owner ? lens[bid] : 0;
    int alive_o = (owner && 0 < len_o) ? 1 : 0;
    int ti = 0, si = 0;

    for (int step = 0; step < 5000; step++) {
      // --- phase A: gates = G + LUT[last]; pointwise; publish h_new ---
      const int last_b = g_last[b];            // safe: read after prev F4 acquire
      const float* lrow = g_lut + (size_t)last_b * 2560;
      double gate1 = G1 + (double)lrow[col1];
      double gate2 = G2 + (double)lrow[col2];
      double x1 = __shfl_xor(gate1, 4, 64);    // partner holds (f,o)
      double x2 = __shfl_xor(gate2, 4, 64);
      double cn = 0.0; float hn = 0.f;
      if (c0 < 4) {
        float fi = (float)gate1, fg = (float)gate2, ff = (float)x1, fo = (float)x2;
        cn = (double)sigmf(ff) * ccur + (double)sigmf(fi) * (double)tanhf(fg);
        hn = sigmf(fo) * tanhf((float)cn);
        g_hnew[(step & 1) * 20480 + b * 640 + u0 + c0] = hn;
      }
      __syncthreads();
      if (tid == 0) bump(F1L + (bid >> 4), F1R, step);
      waitc(F1R, (u32)(step + 1) * 10u);

      // --- pred dot: tanhvec col j (split-k x2 over lane pairs) ---
      {
        const float* hb = g_hnew + (step & 1) * 20480 + b * 640 + half * 320;
        double a = 0.0;
        for (int k = 0; k < 320; k += 4) {
          float4 h4 = *(const float4*)(hb + k);
          float4 q = *(const float4*)(wp + k);
          a += (double)h4.x * q.x; a += (double)h4.y * q.y;
          a += (double)h4.z * q.z; a += (double)h4.w * q.w;
        }
        a += __shfl_xor(a, 1, 64);
        if (half == 0) {
          double pre = (double)g_encT[(size_t)ti * 20480 + b * 640 + j] + a;
          g_tnh[b * 640 + j] = tanhf((float)pre);
        }
      }
      __syncthreads();
      if (tid == 0) bump(F2L + (bid >> 4), F2R, step);

      // --- phase B: speculative G_spec = h_new @ Wh (overlaps out round) ---
      const float* hb = g_hnew + (step & 1) * 20480 + b * 640;
      double a1 = 0.0, a2 = 0.0;
      for (int k = 0; k < 640; k += 4) {
        float4 h4 = *(const float4*)(hb + k);
        float4 q1 = *(const float4*)(w1 + k);
        float4 q2 = *(const float4*)(w2 + k);
        a1 += (double)h4.x * q1.x; a1 += (double)h4.y * q1.y;
        a1 += (double)h4.z * q1.z; a1 += (double)h4.w * q1.w;
        a2 += (double)h4.x * q2.x; a2 += (double)h4.y * q2.y;
        a2 += (double)h4.z * q2.z; a2 += (double)h4.w * q2.w;
      }

      // --- F3: owners reduce 129 candidates for their row; publish last/emit ---
      waitc(F3R, (u32)(step + 1) * 9u);
      if (owner) {
        if (tid < 64) {
          double bv = g_cval[bid * 132 + tid]; int bi = g_cidx[bid * 132 + tid];
          double v1 = g_cval[bid * 132 + tid + 64]; int i1 = g_cidx[bid * 132 + tid + 64];
          if (v1 > bv || (v1 == bv && i1 < bi)) { bv = v1; bi = i1; }
          if (tid == 0) {
            double v2 = g_cval[bid * 132 + 128]; int i2 = g_cidx[bid * 132 + 128];
            if (v2 > bv || (v2 == bv && i2 < bi)) { bv = v2; bi = i2; }
          }
#pragma unroll
          for (int m = 1; m < 64; m <<= 1) {
            double vv = __shfl_xor(bv, m, 64);
            int ii = __shfl_xor(bi, m, 64);
            if (vv > bv || (vv == bv && ii < bi)) { bv = vv; bi = ii; }
          }
          if (tid == 0) {
            int sym = bi;
            int em = (alive_o && sym != 1024) ? 1 : 0;
            out[(size_t)bid * 5000 + step] = (float)(em ? sym : 1024);
            g_emit[bid] = em;
            if (em) g_last[bid] = sym;
            alive_o = (si == 4) ? ((ti + 1 < len_o) ? 1 : 0) : em;
          }
        }
        __syncthreads();  // owner stores drained before release in bump
        if (tid == 0) bump(F4L + (bid >> 4), F4R, step);
      }
      // --- commit on emit ---
      waitc(F4R, (u32)(step + 1) * 2u);
      if (g_emit[b]) {
        G1 = a1; G2 = a2;
        if (c0 < 4) { ccur = cn; hcur = hn; }
      }
      si++; if (si == 5) { si = 0; ti++; }
    }
    if (c0 < 4) {  // cache_rnn_state = stack([h, c])
      out[160000 + b * 640 + u0 + c0] = hcur;
      out[160000 + 20480 + b * 640 + u0 + c0] = (float)ccur;
    }

  } else {
    // ============ OUT role: 8 Wout cols each; block 128 = blank col ============
    const int o = bid - NGB;         // 0..128
    const int b = tid >> 3, c = tid & 7;
    const int gcol = o * 8 + c;
    const bool valid = (gcol <= 1024);
    const int col = valid ? gcol : 1024;
    for (int idx = tid; idx < 8 * 640; idx += 256) {
      int ci = idx / 640, k = idx - ci * 640;
      int gc = o * 8 + ci;
      wsl[ci * LDSTR + k] = (gc <= 1024) ? Wout[(size_t)k * 1025 + gc] : 0.f;
    }
    __syncthreads();
    const double bo = (double)b_out[col];
    const float* wv = &wsl[c * LDSTR];

    for (int step = 0; step < 5000; step++) {
      waitc(F2R, (u32)(step + 1) * 10u);
      const float* tb = g_tnh + b * 640;
      double a = bo;
      for (int k = 0; k < 640; k += 4) {
        float4 t4 = *(const float4*)(tb + k);
        float4 q = *(const float4*)(wv + k);
        a += (double)t4.x * q.x; a += (double)t4.y * q.y;
        a += (double)t4.z * q.z; a += (double)t4.w * q.w;
      }
      double bv = valid ? a : -1.0e300;
      int bi = valid ? col : 0x7fffffff;
#pragma unroll
      for (int m = 1; m < 8; m <<= 1) {  // argmax over this block's 8 cols
        double v2 = __shfl_xor(bv, m, 64);
        int i2 = __shfl_xor(bi, m, 64);
        if (v2 > bv || (v2 == bv && i2 < bi)) { bv = v2; bi = i2; }
      }
      if (c == 0) { g_cval[b * 132 + o] = bv; g_cidx[b * 132 + o] = bi; }
      __syncthreads();
      if (tid == 0) {
        if (o < 128) {
          bump(F3L + (o >> 4), F3R, step);
        } else {  // single blank block: direct root add
          __builtin_amdgcn_fence(__ATOMIC_RELEASE, "agent");
          __hip_atomic_fetch_add(&g_cnt[F3R * 32], 1u, __ATOMIC_RELAXED, __HIP_MEMORY_SCOPE_AGENT);
        }
      }
    }
  }
}

extern "C" void kernel_launch(void* const* d_in, const int* in_sizes, int n_in,
                              void* d_out, int out_size, void* d_ws, size_t ws_size,
                              hipStream_t stream) {
  const float* enc = (const float*)d_in[0];
  const int* lens = (const int*)d_in[1];
  const float* embed = (const float*)d_in[2];
  const float* Wx = (const float*)d_in[3];
  const float* Wh = (const float*)d_in[4];
  const float* b_lstm = (const float*)d_in[5];
  const float* Wenc = (const float*)d_in[6];
  const float* Wpred = (const float*)d_in[7];
  const float* b_joint = (const float*)d_in[8];
  const float* Wout = (const float*)d_in[9];
  const float* b_out = (const float*)d_in[10];
  float* out = (float*)d_out;
  (void)d_ws; (void)ws_size; (void)in_sizes; (void)n_in; (void)out_size;

  hipLaunchKernelGGL(k_lut, dim3(1290), dim3(256), 0, stream, embed, Wx, b_lstm);
  hipLaunchKernelGGL(k_encproj, dim3(160, 32), dim3(256), 0, stream, enc, Wenc, b_joint);
  hipLaunchKernelGGL(k_decode, dim3(NBLK), dim3(256), 0, stream,
                     out, lens, Wh, Wpred, Wout, b_out);
}